// Round 1
// baseline (305.361 us; speedup 1.0000x reference)
//
#include <hip/hip_runtime.h>
#include <hip/hip_bf16.h>
#include <stdint.h>

typedef __bf16 bf16x8 __attribute__((ext_vector_type(8)));
typedef float f32x4 __attribute__((ext_vector_type(4)));

static constexpr int Bn = 8, Sn = 4096, En = 128;

__device__ inline unsigned short f2bf(float f) {
  unsigned u = __builtin_bit_cast(unsigned, f);
  u += 0x7fffu + ((u >> 16) & 1u);
  return (unsigned short)(u >> 16);
}

// ---------------- Kernel 1: fused QKV projection + bias + PReLU ----------------
// x [32768][128] f32 -> qo,ko row-major bf16 [32768][128]; vto transposed bf16 [B][E][S]
__global__ __launch_bounds__(256) void qkv_kernel(
    const float* __restrict__ x,
    const float* __restrict__ Wq, const float* __restrict__ bq, const float* __restrict__ aq,
    const float* __restrict__ Wk, const float* __restrict__ bk, const float* __restrict__ ak,
    const float* __restrict__ Wv, const float* __restrict__ bv, const float* __restrict__ av,
    unsigned short* __restrict__ qo, unsigned short* __restrict__ ko,
    unsigned short* __restrict__ vto)
{
  __shared__ __align__(16) unsigned short xs[64 * 136];   // 64 rows, padded stride 136
  __shared__ __align__(16) unsigned short wsh[128 * 136]; // one W matrix, padded
  const int tid = threadIdx.x;
  const int r0 = blockIdx.x * 64;

  // stage x tile (fp32 -> bf16): 64*32 float4 chunks
  for (int i = 0; i < 8; ++i) {
    int cid = tid + i * 256;
    int row = cid >> 5, c4 = cid & 31;
    const float4 v = *(const float4*)&x[(size_t)(r0 + row) * 128 + c4 * 4];
    unsigned short* d = &xs[row * 136 + c4 * 4];
    d[0] = f2bf(v.x); d[1] = f2bf(v.y); d[2] = f2bf(v.z); d[3] = f2bf(v.w);
  }

  const int lane = tid & 63, wid = tid >> 6;
  const int g = lane >> 4, ln = lane & 15;
  const float* Ws[3] = {Wq, Wk, Wv};
  const float* Bs[3] = {bq, bk, bv};
  const float* As[3] = {aq, ak, av};
  bf16x8 afrag[4];

  for (int mat = 0; mat < 3; ++mat) {
    __syncthreads();  // x staged (iter 0) / previous compute done reading wsh
    // stage W (fp32 -> bf16): 128*32 float4 chunks
    for (int i = 0; i < 16; ++i) {
      int cid = tid + i * 256;
      int row = cid >> 5, c4 = cid & 31;
      const float4 v = *(const float4*)&Ws[mat][row * 128 + c4 * 4];
      unsigned short* d = &wsh[row * 136 + c4 * 4];
      d[0] = f2bf(v.x); d[1] = f2bf(v.y); d[2] = f2bf(v.z); d[3] = f2bf(v.w);
    }
    __syncthreads();

    if (mat == 0) {
      for (int ks = 0; ks < 4; ++ks)
        afrag[ks] = *(const bf16x8*)&xs[(wid * 16 + ln) * 136 + ks * 32 + g * 8];
    }
    const float alpha = As[mat][0];
    f32x4 acc[8];
    for (int nt = 0; nt < 8; ++nt) acc[nt] = (f32x4)(0.f);
    for (int nt = 0; nt < 8; ++nt)
      for (int ks = 0; ks < 4; ++ks) {
        bf16x8 bfrag = *(const bf16x8*)&wsh[(nt * 16 + ln) * 136 + ks * 32 + g * 8];
        acc[nt] = __builtin_amdgcn_mfma_f32_16x16x32_bf16(afrag[ks], bfrag, acc[nt], 0, 0, 0);
      }
    // epilogue: bias + PReLU + store
    const int mbase = r0 + wid * 16 + g * 4;  // 4 consecutive output rows (reg r)
    for (int nt = 0; nt < 8; ++nt) {
      const int n = nt * 16 + ln;
      const float bias = Bs[mat][n];
      float vv[4];
      for (int r = 0; r < 4; ++r) {
        float t = acc[nt][r] + bias;
        vv[r] = t >= 0.f ? t : alpha * t;
      }
      if (mat == 0) {
        for (int r = 0; r < 4; ++r) qo[(size_t)(mbase + r) * 128 + n] = f2bf(vv[r]);
      } else if (mat == 1) {
        for (int r = 0; r < 4; ++r) ko[(size_t)(mbase + r) * 128 + n] = f2bf(vv[r]);
      } else {
        const int b = mbase >> 12, s = mbase & 4095;
        ushort4 pk;
        pk.x = f2bf(vv[0]); pk.y = f2bf(vv[1]); pk.z = f2bf(vv[2]); pk.w = f2bf(vv[3]);
        *(ushort4*)&vto[(size_t)b * (En * Sn) + (size_t)n * Sn + s] = pk;
      }
    }
  }
}

// ---------------- Kernel 2: flash attention fwd, bf16, D=128 ----------------
// q,k row-major bf16 [B][S][128]; vt bf16 [B][128][S]; out f32 [B][S][128]
__global__ __launch_bounds__(256) void attn_kernel(
    const unsigned short* __restrict__ q,
    const unsigned short* __restrict__ k,
    const unsigned short* __restrict__ vt,
    float* __restrict__ out)
{
  __shared__ __align__(16) unsigned short Ks[64 * 136];   // [key][e], padded
  __shared__ __align__(16) unsigned short Vs[128 * 72];   // [e][key], padded
  __shared__ __align__(16) unsigned short Pl[4][16 * 72]; // per-wave P, padded
  const int tid = threadIdx.x;
  const int b = blockIdx.x >> 6, qt = blockIdx.x & 63;
  const int lane = tid & 63, wid = tid >> 6;
  const int g = lane >> 4, ln = lane & 15;
  const size_t bOff = (size_t)b * Sn * En;
  const unsigned short* kb = &k[bOff];
  const unsigned short* vb = &vt[(size_t)b * En * Sn];

  // Q A-fragments: row = lane&15, k-elems = (lane>>4)*8 + j
  const int qrow = qt * 64 + wid * 16 + ln;
  bf16x8 qf[4];
  for (int ks = 0; ks < 4; ++ks)
    qf[ks] = *(const bf16x8*)&q[bOff + (size_t)qrow * 128 + ks * 32 + g * 8];

  f32x4 accO[8];
  for (int e = 0; e < 8; ++e) accO[e] = (f32x4)(0.f);
  float mrow[4], lrow[4];
  for (int r = 0; r < 4; ++r) { mrow[r] = -3.0e38f; lrow[r] = 0.f; }

  for (int kt = 0; kt < 64; ++kt) {
    const int key0 = kt * 64;
    __syncthreads();  // previous compute done reading Ks/Vs
    // stage K tile [64][128]
    for (int i = 0; i < 4; ++i) {
      int cid = tid + i * 256;
      int row = cid >> 4, c = cid & 15;
      uint4 d = *(const uint4*)&kb[(size_t)(key0 + row) * 128 + c * 8];
      *(uint4*)&Ks[row * 136 + c * 8] = d;
    }
    // stage Vt tile [128][64]
    for (int i = 0; i < 4; ++i) {
      int cid = tid + i * 256;
      int row = cid >> 3, c = cid & 7;
      uint4 d = *(const uint4*)&vb[(size_t)row * Sn + key0 + c * 8];
      *(uint4*)&Vs[row * 72 + c * 8] = d;
    }
    __syncthreads();

    // S = Q * K^T  (16 rows x 64 keys per wave)
    f32x4 sacc[4];
    for (int t = 0; t < 4; ++t) sacc[t] = (f32x4)(0.f);
    for (int t = 0; t < 4; ++t)
      for (int ks = 0; ks < 4; ++ks) {
        bf16x8 kf = *(const bf16x8*)&Ks[(t * 16 + ln) * 136 + ks * 32 + g * 8];
        sacc[t] = __builtin_amdgcn_mfma_f32_16x16x32_bf16(qf[ks], kf, sacc[t], 0, 0, 0);
      }

    const float scale = 0.08838834764831845f;  // 1/sqrt(128)
    float alpha_r[4];
    for (int r = 0; r < 4; ++r) {
      float sv[4];
      float vmax = -3.0e38f;
      for (int t = 0; t < 4; ++t) { sv[t] = sacc[t][r] * scale; vmax = fmaxf(vmax, sv[t]); }
      for (int off = 1; off < 16; off <<= 1) vmax = fmaxf(vmax, __shfl_xor(vmax, off, 64));
      float mnew = fmaxf(mrow[r], vmax);
      float al = __expf(mrow[r] - mnew);
      mrow[r] = mnew;
      float rs = 0.f;
      for (int t = 0; t < 4; ++t) { sv[t] = __expf(sv[t] - mnew); rs += sv[t]; }
      for (int off = 1; off < 16; off <<= 1) rs += __shfl_xor(rs, off, 64);
      lrow[r] = lrow[r] * al + rs;
      alpha_r[r] = al;
      for (int t = 0; t < 4; ++t)
        Pl[wid][(g * 4 + r) * 72 + t * 16 + ln] = f2bf(sv[t]);
    }
    for (int e = 0; e < 8; ++e)
      for (int r = 0; r < 4; ++r) accO[e][r] *= alpha_r[r];

    // O += P * V   (A = P[16x64] from per-wave LDS, B = V from Vs transposed tile)
    bf16x8 pf[2];
    for (int ks2 = 0; ks2 < 2; ++ks2)
      pf[ks2] = *(const bf16x8*)&Pl[wid][ln * 72 + ks2 * 32 + g * 8];
    for (int e = 0; e < 8; ++e)
      for (int ks2 = 0; ks2 < 2; ++ks2) {
        bf16x8 vf = *(const bf16x8*)&Vs[(e * 16 + ln) * 72 + ks2 * 32 + g * 8];
        accO[e] = __builtin_amdgcn_mfma_f32_16x16x32_bf16(pf[ks2], vf, accO[e], 0, 0, 0);
      }
  }

  // epilogue: divide by l, store f32
  const int orow = qt * 64 + wid * 16 + g * 4;
  for (int r = 0; r < 4; ++r) {
    float inv = 1.f / lrow[r];
    for (int e = 0; e < 8; ++e)
      out[bOff + (size_t)(orow + r) * 128 + e * 16 + ln] = accO[e][r] * inv;
  }
}

extern "C" void kernel_launch(void* const* d_in, const int* in_sizes, int n_in,
                              void* d_out, int out_size, void* d_ws, size_t ws_size,
                              hipStream_t stream) {
  const float* x  = (const float*)d_in[0];
  const float* Wq = (const float*)d_in[1];
  const float* bq = (const float*)d_in[2];
  const float* aq = (const float*)d_in[3];
  const float* Wk = (const float*)d_in[4];
  const float* bk = (const float*)d_in[5];
  const float* ak = (const float*)d_in[6];
  const float* Wv = (const float*)d_in[7];
  const float* bv = (const float*)d_in[8];
  const float* av = (const float*)d_in[9];

  unsigned short* qws = (unsigned short*)d_ws;
  unsigned short* kws = qws + (size_t)Bn * Sn * En;
  unsigned short* vws = kws + (size_t)Bn * Sn * En;

  qkv_kernel<<<512, 256, 0, stream>>>(x, Wq, bq, aq, Wk, bk, ak, Wv, bv, av,
                                      qws, kws, vws);
  attn_kernel<<<512, 256, 0, stream>>>(qws, kws, vws, (float*)d_out);
}

// Round 4
// 178.663 us; speedup vs baseline: 1.7091x; 1.7091x over previous
//
#include <hip/hip_runtime.h>
#include <hip/hip_bf16.h>
#include <stdint.h>

typedef __bf16 bf16x8 __attribute__((ext_vector_type(8)));
typedef float f32x4 __attribute__((ext_vector_type(4)));
typedef float f32x16 __attribute__((ext_vector_type(16)));
typedef unsigned int u32x4 __attribute__((ext_vector_type(4)));

static constexpr int Bn = 8, Sn = 4096, En = 128;

__device__ __forceinline__ unsigned short f2bf(float f) {
  unsigned u = __builtin_bit_cast(unsigned, f);
  u += 0x7fffu + ((u >> 16) & 1u);
  return (unsigned short)(u >> 16);
}

__device__ __forceinline__ unsigned cvtpk(float a, float b) {
  unsigned r;
  asm("v_cvt_pk_bf16_f32 %0, %1, %2" : "=v"(r) : "v"(a), "v"(b));
  return r;
}

// v_permlane32_swap_b32 vdst, vsrc: vdst.hi <-> vsrc.lo.
// After plswap(a,b): a = {lo lanes: old a@lo, hi lanes: old b@lo},
//                    b = {lo lanes: old a@hi, hi lanes: old b@hi}.
__device__ __forceinline__ void plswap(unsigned &a, unsigned &b) {
  asm("v_permlane32_swap_b32 %0, %1" : "+v"(a), "+v"(b));
}

// ---------------- Kernel 1: fused QKV projection + bias + PReLU ----------------
__global__ __launch_bounds__(256) void qkv_kernel(
    const float* __restrict__ x,
    const float* __restrict__ Wq, const float* __restrict__ bq, const float* __restrict__ aq,
    const float* __restrict__ Wk, const float* __restrict__ bk, const float* __restrict__ ak,
    const float* __restrict__ Wv, const float* __restrict__ bv, const float* __restrict__ av,
    unsigned short* __restrict__ qo, unsigned short* __restrict__ ko,
    unsigned short* __restrict__ vto)
{
  __shared__ __align__(16) unsigned short xs[64 * 136];
  __shared__ __align__(16) unsigned short wsh[128 * 136];
  const int tid = threadIdx.x;
  const int r0 = blockIdx.x * 64;

  for (int i = 0; i < 8; ++i) {
    int cid = tid + i * 256;
    int row = cid >> 5, c4 = cid & 31;
    const float4 v = *(const float4*)&x[(size_t)(r0 + row) * 128 + c4 * 4];
    unsigned short* d = &xs[row * 136 + c4 * 4];
    d[0] = f2bf(v.x); d[1] = f2bf(v.y); d[2] = f2bf(v.z); d[3] = f2bf(v.w);
  }

  const int lane = tid & 63, wid = tid >> 6;
  const int g = lane >> 4, ln = lane & 15;
  const float* Ws[3] = {Wq, Wk, Wv};
  const float* Bs[3] = {bq, bk, bv};
  const float* As[3] = {aq, ak, av};
  bf16x8 afrag[4];

  for (int mat = 0; mat < 3; ++mat) {
    __syncthreads();
    for (int i = 0; i < 16; ++i) {
      int cid = tid + i * 256;
      int row = cid >> 5, c4 = cid & 31;
      const float4 v = *(const float4*)&Ws[mat][row * 128 + c4 * 4];
      unsigned short* d = &wsh[row * 136 + c4 * 4];
      d[0] = f2bf(v.x); d[1] = f2bf(v.y); d[2] = f2bf(v.z); d[3] = f2bf(v.w);
    }
    __syncthreads();

    if (mat == 0) {
      for (int ks = 0; ks < 4; ++ks)
        afrag[ks] = *(const bf16x8*)&xs[(wid * 16 + ln) * 136 + ks * 32 + g * 8];
    }
    const float alpha = As[mat][0];
    f32x4 acc[8];
    for (int nt = 0; nt < 8; ++nt) acc[nt] = (f32x4)(0.f);
    for (int nt = 0; nt < 8; ++nt)
      for (int ks = 0; ks < 4; ++ks) {
        bf16x8 bfrag = *(const bf16x8*)&wsh[(nt * 16 + ln) * 136 + ks * 32 + g * 8];
        acc[nt] = __builtin_amdgcn_mfma_f32_16x16x32_bf16(afrag[ks], bfrag, acc[nt], 0, 0, 0);
      }
    const int mbase = r0 + wid * 16 + g * 4;
    for (int nt = 0; nt < 8; ++nt) {
      const int n = nt * 16 + ln;
      const float bias = Bs[mat][n];
      float vv[4];
      for (int r = 0; r < 4; ++r) {
        float t = acc[nt][r] + bias;
        vv[r] = t >= 0.f ? t : alpha * t;
      }
      if (mat == 0) {
        for (int r = 0; r < 4; ++r) qo[(size_t)(mbase + r) * 128 + n] = f2bf(vv[r]);
      } else if (mat == 1) {
        for (int r = 0; r < 4; ++r) ko[(size_t)(mbase + r) * 128 + n] = f2bf(vv[r]);
      } else {
        const int b = mbase >> 12, s = mbase & 4095;
        ushort4 pk;
        pk.x = f2bf(vv[0]); pk.y = f2bf(vv[1]); pk.z = f2bf(vv[2]); pk.w = f2bf(vv[3]);
        *(ushort4*)&vto[(size_t)b * (En * Sn) + (size_t)n * Sn + s] = pk;
      }
    }
  }
}

// ---------------- Kernel 2: flash attention, swapped-QK 32x32, O^T accum ----------------
__device__ __forceinline__ void load_tiles(const char* kg, const char* vg, int key0,
                                           int tid, uint4* kreg, uint4* vreg) {
  const char* ksrc = kg + (size_t)key0 * 256;
  #pragma unroll
  for (int i = 0; i < 4; ++i) kreg[i] = *(const uint4*)(ksrc + (tid + i * 256) * 16);
  #pragma unroll
  for (int i = 0; i < 4; ++i) {
    int o = (tid + i * 256) * 16;
    vreg[i] = *(const uint4*)(vg + (size_t)(o >> 7) * 8192 + (size_t)key0 * 2 + (o & 127));
  }
}

__device__ __forceinline__ void store_tiles(char* kd, char* vd, int tid,
                                            const uint4* kreg, const uint4* vreg) {
  #pragma unroll
  for (int i = 0; i < 4; ++i) {
    int o = (tid + i * 256) * 16;
    *(uint4*)(kd + (o ^ (((o >> 8) & 7) << 4))) = kreg[i];
  }
  #pragma unroll
  for (int i = 0; i < 4; ++i) {
    int o = (tid + i * 256) * 16;
    *(uint4*)(vd + (o ^ (((o >> 7) & 7) << 4))) = vreg[i];
  }
}

template <int KSPLIT>
__global__ __launch_bounds__(256, 2) void attn_kernel(
    const unsigned short* __restrict__ q,
    const unsigned short* __restrict__ k,
    const unsigned short* __restrict__ vt,
    float* __restrict__ opart, float* __restrict__ mpart,
    float* __restrict__ lpart, float* __restrict__ out)
{
  __shared__ __align__(16) char smem[65536];  // K dbuf 2x16K | V^T dbuf 2x16K
  const int tid = threadIdx.x;
  const int lane = tid & 63, wid = tid >> 6;
  const int qt = blockIdx.x & 31;
  const int b  = (blockIdx.x >> 5) & 7;
  const int kh = blockIdx.x >> 8;          // 0 when KSPLIT==1
  const int hi = lane >> 5, ln = lane & 31;
  const size_t bOff = (size_t)b * Sn * En;
  const char* kg = (const char*)(k + bOff);
  const char* vg = (const char*)(vt + (size_t)b * En * Sn);

  // Q fragments (B-operand of swapped QK): col=q=ln, k-elems e=16s+8hi+j
  const int qrow = qt * 128 + wid * 32 + ln;
  bf16x8 qf[8];
  #pragma unroll
  for (int s = 0; s < 8; ++s)
    qf[s] = *(const bf16x8*)((const char*)(q + bOff) + (size_t)qrow * 256 + s * 32 + hi * 16);

  f32x16 acc[4];   // O^T accum: acc[et], col=q=ln, row e = 32*et + (reg&3)+8*(reg>>2)+4*hi
  #pragma unroll
  for (int et = 0; et < 4; ++et) acc[et] = (f32x16)(0.f);
  float m_run = -1e30f, lsum = 0.f;

  const int nkt = (Sn / KSPLIT) / 64;
  const int kbase = kh * (Sn / KSPLIT);
  const float cst = 1.4426950408889634f * 0.08838834764831845f;  // log2(e)/sqrt(128)

  uint4 kreg[4], vreg[4];
  // prologue: stage tile 0, prefetch tile 1 into regs
  load_tiles(kg, vg, kbase, tid, kreg, vreg);
  store_tiles(smem, smem + 32768, tid, kreg, vreg);
  if (nkt > 1) load_tiles(kg, vg, kbase + 64, tid, kreg, vreg);
  __syncthreads();

  for (int kt = 0; kt < nkt; ++kt) {
    const char* kl = smem + (kt & 1) * 16384;
    const char* vl = smem + 32768 + (kt & 1) * 16384;

    // ---- QK^T (swapped): S^T = K * Q, two 32-key subtiles ----
    f32x16 st0 = (f32x16)(0.f), st1 = (f32x16)(0.f);
    #pragma unroll
    for (int s = 0; s < 8; ++s) {
      const int cb = (32 * s + 16 * hi) ^ ((ln & 7) << 4);
      bf16x8 kf0 = *(const bf16x8*)(kl + ln * 256 + cb);
      bf16x8 kf1 = *(const bf16x8*)(kl + (32 + ln) * 256 + cb);
      st0 = __builtin_amdgcn_mfma_f32_32x32x16_bf16(kf0, qf[s], st0, 0, 0, 0);
      st1 = __builtin_amdgcn_mfma_f32_32x32x16_bf16(kf1, qf[s], st1, 0, 0, 0);
    }

    // ---- online softmax (per-lane row q=ln; duplicated across hi) ----
    float t16[16];
    #pragma unroll
    for (int i = 0; i < 16; ++i) t16[i] = fmaxf(st0[i], st1[i]);
    float t8[8];
    #pragma unroll
    for (int i = 0; i < 8; ++i) t8[i] = fmaxf(t16[i], t16[i + 8]);
    float t4[4];
    #pragma unroll
    for (int i = 0; i < 4; ++i) t4[i] = fmaxf(t8[i], t8[i + 4]);
    float vtile = fmaxf(fmaxf(t4[0], t4[1]), fmaxf(t4[2], t4[3])) * cst;
    vtile = fmaxf(vtile, __shfl_xor(vtile, 32));

    if (__any(vtile > m_run + 8.0f)) {      // defer-max: rescale only on real growth
      float mnew = fmaxf(m_run, vtile);
      float al = __builtin_amdgcn_exp2f(m_run - mnew);
      #pragma unroll
      for (int et = 0; et < 4; ++et) acc[et] *= al;
      lsum *= al;
      m_run = mnew;
    }

    float p[32];
    #pragma unroll
    for (int i = 0; i < 16; ++i) p[i]      = __builtin_amdgcn_exp2f(fmaf(st0[i], cst, -m_run));
    #pragma unroll
    for (int i = 0; i < 16; ++i) p[16 + i] = __builtin_amdgcn_exp2f(fmaf(st1[i], cst, -m_run));

    float s16[16];
    #pragma unroll
    for (int i = 0; i < 16; ++i) s16[i] = p[i] + p[16 + i];
    float s8[8];
    #pragma unroll
    for (int i = 0; i < 8; ++i) s8[i] = s16[i] + s16[i + 8];
    float s4[4];
    #pragma unroll
    for (int i = 0; i < 4; ++i) s4[i] = s8[i] + s8[i + 4];
    float tsum = (s4[0] + s4[1]) + (s4[2] + s4[3]);
    tsum += __shfl_xor(tsum, 32);
    lsum += tsum;

    // ---- pack P -> bf16 B-fragments via cvt_pk + permlane32_swap ----
    // wa[g2] = bf16 pair (keys 8*g2+4*hi + {0,1}), wb[g2] = keys + {2,3}.
    unsigned wa[8], wb[8];
    #pragma unroll
    for (int g2 = 0; g2 < 8; ++g2) {
      wa[g2] = cvtpk(p[4 * g2], p[4 * g2 + 1]);
      wb[g2] = cvtpk(p[4 * g2 + 2], p[4 * g2 + 3]);
    }
    // pb[ks] dword j holds P[q=ln][key = 16*ks + 8*hi + 2*j + {0,1}]:
    //   dword0 = first result of plswap(wa[2ks], wa[2ks+1]), dword2 = second.
    bf16x8 pb[4];
    #pragma unroll
    for (int ks = 0; ks < 4; ++ks) {
      unsigned w0 = wa[2 * ks], w2 = wa[2 * ks + 1];
      plswap(w0, w2);
      unsigned w1 = wb[2 * ks], w3 = wb[2 * ks + 1];
      plswap(w1, w3);
      u32x4 w = {w0, w1, w2, w3};
      pb[ks] = __builtin_bit_cast(bf16x8, w);
    }

    // ---- PV (transposed): O^T += V^T * P^T ----
    #pragma unroll
    for (int ks = 0; ks < 4; ++ks) {
      const int cb = (32 * ks + 16 * hi) ^ ((ln & 7) << 4);
      #pragma unroll
      for (int et = 0; et < 4; ++et) {
        bf16x8 vf = *(const bf16x8*)(vl + (32 * et + ln) * 128 + cb);
        acc[et] = __builtin_amdgcn_mfma_f32_32x32x16_bf16(vf, pb[ks], acc[et], 0, 0, 0);
      }
    }

    __syncthreads();
    if (kt + 1 < nkt) {
      store_tiles(smem + ((kt + 1) & 1) * 16384,
                  smem + 32768 + ((kt + 1) & 1) * 16384, tid, kreg, vreg);
      if (kt + 2 < nkt) load_tiles(kg, vg, kbase + (kt + 2) * 64, tid, kreg, vreg);
      __syncthreads();
    }
  }

  // ---- epilogue: per-wave LDS transpose O^T -> row-major, coalesced store ----
  __syncthreads();
  char* sl = smem + wid * 16384;            // 32 q-rows x 512 B each
  const float inv = (KSPLIT == 1) ? (1.0f / lsum) : 1.0f;
  #pragma unroll
  for (int et = 0; et < 4; ++et)
    #pragma unroll
    for (int rg = 0; rg < 4; ++rg) {
      f32x4 v;
      #pragma unroll
      for (int j = 0; j < 4; ++j) v[j] = acc[et][rg * 4 + j] * inv;
      const int addr = ln * 512 + et * 128 + rg * 32 + hi * 16;
      *(f32x4*)(sl + (addr ^ ((ln & 7) << 4))) = v;
    }
  __builtin_amdgcn_s_waitcnt(0);            // drain lgkm before wave-local readback
  char* obase;
  if (KSPLIT == 2)
    obase = (char*)(opart + ((size_t)(kh * Bn + b) * Sn + qt * 128 + wid * 32) * En);
  else
    obase = (char*)(out + ((size_t)b * Sn + qt * 128 + wid * 32) * En);
  // 32 rows x 512 B = 16 KB per wave; 64 lanes x 16 B = 1 KB per iter -> 16 iters.
  #pragma unroll
  for (int i = 0; i < 16; ++i) {
    const int flat = i * 1024 + lane * 16;
    const int qr = flat >> 9, col = flat & 511;
    f32x4 v = *(const f32x4*)(sl + ((qr * 512 + col) ^ ((qr & 7) << 4)));
    *(f32x4*)(obase + (size_t)qr * 512 + col) = v;
  }
  if (KSPLIT == 2 && lane < 32) {
    const size_t idx = (size_t)(kh * Bn + b) * Sn + qt * 128 + wid * 32 + ln;
    mpart[idx] = m_run;
    lpart[idx] = lsum;
  }
}

// ---------------- Kernel 3: merge the two K-halves ----------------
__global__ __launch_bounds__(256) void combine_kernel(
    const float* __restrict__ opart, const float* __restrict__ mpart,
    const float* __restrict__ lpart, float* __restrict__ out)
{
  const int idx = blockIdx.x * 256 + threadIdx.x;   // float4 index
  const int row = idx >> 5;
  const size_t NO = (size_t)Bn * Sn * En / 4;
  f32x4 o1 = ((const f32x4*)opart)[idx];
  f32x4 o2 = ((const f32x4*)opart)[idx + NO];
  const float m1 = mpart[row], m2 = mpart[row + Bn * Sn];
  const float l1 = lpart[row], l2 = lpart[row + Bn * Sn];
  const float m = fmaxf(m1, m2);
  const float w1 = __builtin_amdgcn_exp2f(m1 - m);
  const float w2 = __builtin_amdgcn_exp2f(m2 - m);
  const float inv = 1.0f / (w1 * l1 + w2 * l2);
  ((f32x4*)out)[idx] = (o1 * w1 + o2 * w2) * inv;
}

extern "C" void kernel_launch(void* const* d_in, const int* in_sizes, int n_in,
                              void* d_out, int out_size, void* d_ws, size_t ws_size,
                              hipStream_t stream) {
  const float* x  = (const float*)d_in[0];
  const float* Wq = (const float*)d_in[1];
  const float* bq = (const float*)d_in[2];
  const float* aq = (const float*)d_in[3];
  const float* Wk = (const float*)d_in[4];
  const float* bk = (const float*)d_in[5];
  const float* ak = (const float*)d_in[6];
  const float* Wv = (const float*)d_in[7];
  const float* bv = (const float*)d_in[8];
  const float* av = (const float*)d_in[9];

  const size_t BSE = (size_t)Bn * Sn * En;          // 4,194,304
  unsigned short* qws = (unsigned short*)d_ws;
  unsigned short* kws = qws + BSE;
  unsigned short* vws = kws + BSE;
  float* opart = (float*)((char*)d_ws + 3 * BSE * 2);      // after 24 MB of bf16
  float* mpart = opart + 2 * BSE;
  float* lpart = mpart + 2 * (size_t)Bn * Sn;
  const size_t need2 = 3 * BSE * 2 + 2 * BSE * 4 + 4 * (size_t)Bn * Sn * 4;

  qkv_kernel<<<512, 256, 0, stream>>>(x, Wq, bq, aq, Wk, bk, ak, Wv, bv, av,
                                      qws, kws, vws);
  if (ws_size >= need2) {
    attn_kernel<2><<<512, 256, 0, stream>>>(qws, kws, vws, opart, mpart, lpart,
                                            (float*)d_out);
    combine_kernel<<<4096, 256, 0, stream>>>(opart, mpart, lpart, (float*)d_out);
  } else {
    attn_kernel<1><<<256, 256, 0, stream>>>(qws, kws, vws, opart, mpart, lpart,
                                            (float*)d_out);
  }
}